// Round 13
// baseline (48.812 us; speedup 1.0000x reference)
//
#include <hip/hip_runtime.h>

#define BLK 256
#define NJ 24
#define G 8
#define NG (NJ / G)
#define DREP 6   // DIAGNOSTIC: repeat drain to measure its marginal cost

typedef float vf4 __attribute__((ext_vector_type(4)));  // native vec for nontemporal builtin

__global__ __launch_bounds__(BLK, 2)
void fk_kernel(const float* __restrict__ angles,   // (B, 24)
               const float* __restrict__ Torg,     // (24, 4, 4) row-major
               const float* __restrict__ axes,     // (24, 3)
               float* __restrict__ out,            // (B, 75)
               int B)
{
    __shared__ float stage[BLK * 75];
    __shared__ float sQK[NJ * 8];   // per joint: {qw,qx,qy,qz, otx,oty,otz, pad}
    __shared__ float sAx[NJ * 4];   // axis xyz + pad

    const int tid = threadIdx.x;
    const int b = blockIdx.x * BLK + tid;

    // Prefetch ALL 24 angles up front: 6 float4 loads in flight.
    const float4* ap = reinterpret_cast<const float4*>(angles + (size_t)b * NJ);
    const float4 av0 = ap[0], av1 = ap[1], av2 = ap[2];
    const float4 av3 = ap[3], av4 = ap[4], av5 = ap[5];

    // --- One-time: convert T_org rotations to quaternions (threads 0..23) ---
    if (tid < NJ) {
        const float* o = Torg + tid * 16;
        const float m00=o[0], m01=o[1], m02=o[2];
        const float m10=o[4], m11=o[5], m12=o[6];
        const float m20=o[8], m21=o[9], m22=o[10];
        const float tr = m00 + m11 + m22;
        float qw, qx, qy, qz;
        if (tr > 0.f) {
            const float S = sqrtf(tr + 1.f) * 2.f;
            qw = 0.25f * S;
            qx = (m21 - m12) / S;
            qy = (m02 - m20) / S;
            qz = (m10 - m01) / S;
        } else if (m00 > m11 && m00 > m22) {
            const float S = sqrtf(1.f + m00 - m11 - m22) * 2.f;
            qw = (m21 - m12) / S;
            qx = 0.25f * S;
            qy = (m01 + m10) / S;
            qz = (m02 + m20) / S;
        } else if (m11 > m22) {
            const float S = sqrtf(1.f + m11 - m00 - m22) * 2.f;
            qw = (m02 - m20) / S;
            qx = (m01 + m10) / S;
            qy = 0.25f * S;
            qz = (m12 + m21) / S;
        } else {
            const float S = sqrtf(1.f + m22 - m00 - m11) * 2.f;
            qw = (m10 - m01) / S;
            qx = (m02 + m20) / S;
            qy = (m12 + m21) / S;
            qz = 0.25f * S;
        }
        float* q = &sQK[tid * 8];
        q[0] = qw; q[1] = qx; q[2] = qy; q[3] = qz;
        q[4] = o[3]; q[5] = o[7]; q[6] = o[11]; q[7] = 0.f;   // O_t
        float* ax = &sAx[tid * 4];
        ax[0] = axes[tid*3+0]; ax[1] = axes[tid*3+1]; ax[2] = axes[tid*3+2]; ax[3] = 0.f;
    }
    __syncthreads();

    // Running transform as quaternion Q + translation t.
    float Qw = 1.f, Qx = 0.f, Qy = 0.f, Qz = 0.f;
    float tx = 0.f, ty = 0.f, tz = 0.f;

    float* srow = &stage[tid * 75];
    srow[0] = 0.f; srow[1] = 0.f; srow[2] = 0.f;   // base_pos

    #pragma unroll 1
    for (int g = 0; g < NG; ++g) {
        float a[G];
        if (g == 0) {
            a[0]=av0.x; a[1]=av0.y; a[2]=av0.z; a[3]=av0.w;
            a[4]=av1.x; a[5]=av1.y; a[6]=av1.z; a[7]=av1.w;
        } else if (g == 1) {
            a[0]=av2.x; a[1]=av2.y; a[2]=av2.z; a[3]=av2.w;
            a[4]=av3.x; a[5]=av3.y; a[6]=av3.z; a[7]=av3.w;
        } else {
            a[0]=av4.x; a[1]=av4.y; a[2]=av4.z; a[3]=av4.w;
            a[4]=av5.x; a[5]=av5.y; a[6]=av5.z; a[7]=av5.w;
        }

        // --- Phase A: u_j = qO_j * q_j for 8 joints (independent, ILP) ---
        float U[G][4];
        float OT[G][3];
        #pragma unroll
        for (int u = 0; u < G; ++u) {
            const int j = g * G + u;
            const float4 qo = *reinterpret_cast<const float4*>(&sQK[j*8]);
            const float4 ot = *reinterpret_cast<const float4*>(&sQK[j*8+4]);
            const float4 ax = *reinterpret_cast<const float4*>(&sAx[j*4]);
            OT[u][0] = ot.x; OT[u][1] = ot.y; OT[u][2] = ot.z;

            const float h = 0.5f * a[u];
            const float s = __sinf(h);
            const float c = __cosf(h);
            const float bx = s * ax.x, by = s * ax.y, bz = s * ax.z;

            U[u][0] = qo.x*c  - qo.y*bx - qo.z*by - qo.w*bz;
            U[u][1] = qo.x*bx + qo.y*c  + qo.z*bz - qo.w*by;
            U[u][2] = qo.x*by - qo.y*bz + qo.z*c  + qo.w*bx;
            U[u][3] = qo.x*bz + qo.y*by - qo.z*bx + qo.w*c;
        }

        // --- Phase B: serial chain, short dep path ---
        #pragma unroll
        for (int u = 0; u < G; ++u) {
            const int j = g * G + u;
            const float ox = OT[u][0], oy = OT[u][1], oz = OT[u][2];

            const float cx = Qy*oz - Qz*oy + Qw*ox;
            const float cy = Qz*ox - Qx*oz + Qw*oy;
            const float cz = Qx*oy - Qy*ox + Qw*oz;
            const float dx = Qy*cz - Qz*cy;
            const float dy = Qz*cx - Qx*cz;
            const float dz = Qx*cy - Qy*cx;
            tx = tx + ox + 2.f*dx;
            ty = ty + oy + 2.f*dy;
            tz = tz + oz + 2.f*dz;

            const float uw = U[u][0], ux = U[u][1], uy = U[u][2], uz = U[u][3];
            const float nw = Qw*uw - Qx*ux - Qy*uy - Qz*uz;
            const float nx = Qw*ux + Qx*uw + Qy*uz - Qz*uy;
            const float ny = Qw*uy - Qx*uz + Qy*uw + Qz*ux;
            const float nz = Qw*uz + Qx*uy - Qy*ux + Qz*uw;
            Qw = nw; Qx = nx; Qy = ny; Qz = nz;

            srow[3 + 3*j + 0] = tx;
            srow[3 + 3*j + 1] = ty;
            srow[3 + 3*j + 2] = tz;
        }
    }

    __syncthreads();

    // ===== DIAGNOSTIC: drain repeated DREP times (idempotent). Pointer is
    // laundered per rep so dead-store elimination cannot drop reps 0..4. =====
    #pragma unroll 1
    for (int rep = 0; rep < DREP; ++rep) {
        float* obase = out + (size_t)blockIdx.x * BLK * 75;
        asm volatile("" : "+v"(obase));   // opaque pointer -> no cross-rep DSE
        vf4* out4 = reinterpret_cast<vf4*>(obase);
        const vf4* st4 = reinterpret_cast<const vf4*>(stage);
        #pragma unroll
        for (int k = 0; k < 18; ++k) {
            const vf4 v = st4[tid + k * BLK];
            __builtin_nontemporal_store(v, &out4[tid + k * BLK]);
        }
        if (tid < (BLK * 75 / 4) - 18 * BLK) {   // 4800 - 4608 = 192
            const vf4 v = st4[tid + 18 * BLK];
            __builtin_nontemporal_store(v, &out4[tid + 18 * BLK]);
        }
    }
}

extern "C" void kernel_launch(void* const* d_in, const int* in_sizes, int n_in,
                              void* d_out, int out_size, void* d_ws, size_t ws_size,
                              hipStream_t stream) {
    const float* angles = (const float*)d_in[0];
    const float* Torg   = (const float*)d_in[1];
    const float* axes   = (const float*)d_in[2];
    float* out = (float*)d_out;

    const int B = in_sizes[0] / NJ;          // 131072
    const int grid = (B + BLK - 1) / BLK;    // 512

    fk_kernel<<<grid, BLK, 0, stream>>>(angles, Torg, axes, out, B);
}

// Round 14
// 17.816 us; speedup vs baseline: 2.7398x; 2.7398x over previous
//
#include <hip/hip_runtime.h>

#define BLK 256
#define NJ 24
#define G 8
#define NG (NJ / G)
#define NWV (BLK / 64)

typedef float vf4 __attribute__((ext_vector_type(4)));  // native vec for nontemporal builtin

__global__ __launch_bounds__(BLK, 2)
void fk_kernel(const float* __restrict__ angles,   // (B, 24)
               const float* __restrict__ Torg,     // (24, 4, 4) row-major
               const float* __restrict__ axes,     // (24, 3)
               float* __restrict__ out,            // (B, 75)
               int B)
{
    __shared__ float stage[BLK * 75];            // 76.8 KB
    __shared__ float sP[NWV][NJ * 4];            // per-wave: P_j = qO_j
    __shared__ float sQ[NWV][NJ * 4];            // per-wave: Q_j = qO_j (x) (0,axis_j)
    __shared__ float sOT[NWV][NJ * 4];           // per-wave: origin translation

    const int tid  = threadIdx.x;
    const int lane = tid & 63;
    const int wv   = tid >> 6;
    const int b    = blockIdx.x * BLK + tid;

    // Prefetch ALL 24 angles up front: 6 float4 loads in flight.
    const float4* ap = reinterpret_cast<const float4*>(angles + (size_t)b * NJ);
    const float4 av0 = ap[0], av1 = ap[1], av2 = ap[2];
    const float4 av3 = ap[3], av4 = ap[4], av5 = ap[5];

    // --- Per-wave constant build (lanes 0..23). No block barrier needed:
    // within-wave LDS write->read ordering is lockstep + lgkmcnt. ---
    if (lane < NJ) {
        const float* o = Torg + lane * 16;
        const float m00=o[0], m01=o[1], m02=o[2];
        const float m10=o[4], m11=o[5], m12=o[6];
        const float m20=o[8], m21=o[9], m22=o[10];
        const float tr = m00 + m11 + m22;
        float qw, qx, qy, qz;
        if (tr > 0.f) {
            const float S = sqrtf(tr + 1.f) * 2.f;
            qw = 0.25f * S;
            qx = (m21 - m12) / S;
            qy = (m02 - m20) / S;
            qz = (m10 - m01) / S;
        } else if (m00 > m11 && m00 > m22) {
            const float S = sqrtf(1.f + m00 - m11 - m22) * 2.f;
            qw = (m21 - m12) / S;
            qx = 0.25f * S;
            qy = (m01 + m10) / S;
            qz = (m02 + m20) / S;
        } else if (m11 > m22) {
            const float S = sqrtf(1.f + m11 - m00 - m22) * 2.f;
            qw = (m02 - m20) / S;
            qx = (m01 + m10) / S;
            qy = 0.25f * S;
            qz = (m12 + m21) / S;
        } else {
            const float S = sqrtf(1.f + m22 - m00 - m11) * 2.f;
            qw = (m10 - m01) / S;
            qx = (m02 + m20) / S;
            qy = (m12 + m21) / S;
            qz = 0.25f * S;
        }
        const float axx = axes[lane*3+0], axy = axes[lane*3+1], axz = axes[lane*3+2];
        // Q = qO (x) (0, axis)
        const float Qw_ = -qx*axx - qy*axy - qz*axz;
        const float Qx_ =  qw*axx + qy*axz - qz*axy;
        const float Qy_ =  qw*axy - qx*axz + qz*axx;
        const float Qz_ =  qw*axz + qx*axy - qy*axx;

        float* p = &sP[wv][lane * 4];
        p[0] = qw; p[1] = qx; p[2] = qy; p[3] = qz;
        float* q = &sQ[wv][lane * 4];
        q[0] = Qw_; q[1] = Qx_; q[2] = Qy_; q[3] = Qz_;
        float* t = &sOT[wv][lane * 4];
        t[0] = o[3]; t[1] = o[7]; t[2] = o[11]; t[3] = 0.f;
    }

    // Running transform as quaternion Q + translation t.
    float Qw = 1.f, Qx = 0.f, Qy = 0.f, Qz = 0.f;
    float tx = 0.f, ty = 0.f, tz = 0.f;

    float* srow = &stage[tid * 75];
    srow[0] = 0.f; srow[1] = 0.f; srow[2] = 0.f;   // base_pos

    #pragma unroll 1
    for (int g = 0; g < NG; ++g) {
        float a[G];
        if (g == 0) {
            a[0]=av0.x; a[1]=av0.y; a[2]=av0.z; a[3]=av0.w;
            a[4]=av1.x; a[5]=av1.y; a[6]=av1.z; a[7]=av1.w;
        } else if (g == 1) {
            a[0]=av2.x; a[1]=av2.y; a[2]=av2.z; a[3]=av2.w;
            a[4]=av3.x; a[5]=av3.y; a[6]=av3.z; a[7]=av3.w;
        } else {
            a[0]=av4.x; a[1]=av4.y; a[2]=av4.z; a[3]=av4.w;
            a[4]=av5.x; a[5]=av5.y; a[6]=av5.z; a[7]=av5.w;
        }

        // --- Phase A: U_j = c*P_j + s*Q_j  (8 FMA; linear in cos/sin) ---
        float U[G][4];
        float OT[G][3];
        #pragma unroll
        for (int u = 0; u < G; ++u) {
            const int j = g * G + u;
            const float4 P  = *reinterpret_cast<const float4*>(&sP[wv][j*4]);
            const float4 Qv = *reinterpret_cast<const float4*>(&sQ[wv][j*4]);
            const float4 ot = *reinterpret_cast<const float4*>(&sOT[wv][j*4]);
            OT[u][0] = ot.x; OT[u][1] = ot.y; OT[u][2] = ot.z;

            const float h = 0.5f * a[u];
            const float s = __sinf(h);
            const float c = __cosf(h);

            U[u][0] = c*P.x + s*Qv.x;
            U[u][1] = c*P.y + s*Qv.y;
            U[u][2] = c*P.z + s*Qv.z;
            U[u][3] = c*P.w + s*Qv.w;
        }

        // --- Phase B: serial chain, short dep path ---
        #pragma unroll
        for (int u = 0; u < G; ++u) {
            const int j = g * G + u;
            const float ox = OT[u][0], oy = OT[u][1], oz = OT[u][2];

            // t_child = t + R(Q)*O_t   (v' = v + 2*qv x (qv x v + w v))
            const float cx = Qy*oz - Qz*oy + Qw*ox;
            const float cy = Qz*ox - Qx*oz + Qw*oy;
            const float cz = Qx*oy - Qy*ox + Qw*oz;
            const float dx = Qy*cz - Qz*cy;
            const float dy = Qz*cx - Qx*cz;
            const float dz = Qx*cy - Qy*cx;
            tx = tx + ox + 2.f*dx;
            ty = ty + oy + 2.f*dy;
            tz = tz + oz + 2.f*dz;

            // Q = Q * U[u]   (Hamilton)
            const float uw = U[u][0], ux = U[u][1], uy = U[u][2], uz = U[u][3];
            const float nw = Qw*uw - Qx*ux - Qy*uy - Qz*uz;
            const float nx = Qw*ux + Qx*uw + Qy*uz - Qz*uy;
            const float ny = Qw*uy - Qx*uz + Qy*uw + Qz*ux;
            const float nz = Qw*uz + Qx*uy - Qy*ux + Qz*uw;
            Qw = nw; Qx = nx; Qy = ny; Qz = nz;

            srow[3 + 3*j + 0] = tx;
            srow[3 + 3*j + 1] = ty;
            srow[3 + 3*j + 2] = tz;
        }
    }

    // --- Per-wave drain: each wave flushes ONLY its own 64 rows (contiguous
    // 19.2 KB region). No __syncthreads anywhere: waves desync freely, so
    // early waves' NT stores drain under late waves' compute. ---
    {
        const int rowbase = wv * 64;                 // first row of this wave
        float* obase = out + ((size_t)blockIdx.x * BLK + rowbase) * 75;
        vf4* out4 = reinterpret_cast<vf4*>(obase);
        const vf4* st4 = reinterpret_cast<const vf4*>(&stage[rowbase * 75]);
        // 64*75/4 = 1200 vec4 per wave = 18 full rounds + 48-lane tail
        #pragma unroll
        for (int k = 0; k < 18; ++k) {
            const vf4 v = st4[lane + k * 64];
            __builtin_nontemporal_store(v, &out4[lane + k * 64]);
        }
        if (lane < 1200 - 18 * 64) {                 // 48
            const vf4 v = st4[lane + 18 * 64];
            __builtin_nontemporal_store(v, &out4[lane + 18 * 64]);
        }
    }
}

extern "C" void kernel_launch(void* const* d_in, const int* in_sizes, int n_in,
                              void* d_out, int out_size, void* d_ws, size_t ws_size,
                              hipStream_t stream) {
    const float* angles = (const float*)d_in[0];
    const float* Torg   = (const float*)d_in[1];
    const float* axes   = (const float*)d_in[2];
    float* out = (float*)d_out;

    const int B = in_sizes[0] / NJ;          // 131072
    const int grid = (B + BLK - 1) / BLK;    // 512

    fk_kernel<<<grid, BLK, 0, stream>>>(angles, Torg, axes, out, B);
}